// Round 1
// baseline (572.723 us; speedup 1.0000x reference)
//
#include <hip/hip_runtime.h>
#include <hip/hip_bf16.h>
#include <cstdint>
#include <cstddef>

#define C_DIM   384
#define NIMG    3136      // 56*56
#define MROWS   50176     // 16*3136 tokens
#define QK_SCALE 0.17677669529663687f  // 32^-0.5

using bf16x8 = __attribute__((ext_vector_type(8))) short;   // 8 bf16 in 4 VGPRs
using f32x4  = __attribute__((ext_vector_type(4))) float;

__device__ __forceinline__ short f2bf(float f) {
  union { float f; uint32_t u; } v; v.f = f;
  uint32_t r = (v.u + 0x7fffu + ((v.u >> 16) & 1u)) >> 16;  // RNE
  return (short)(uint16_t)r;
}

__device__ __forceinline__ float bf2f(short s) {
  union { uint32_t u; float f; } v; v.u = ((uint32_t)(uint16_t)s) << 16;
  return v.f;
}

__device__ __forceinline__ void async_copy16(const void* g, void* l) {
  __builtin_amdgcn_global_load_lds(
      (const __attribute__((address_space(1))) void*)g,
      (__attribute__((address_space(3))) void*)l, 16, 0, 0);
}

__device__ __forceinline__ float gelu_exact(float x) {
  return 0.5f * x * (1.0f + erff(x * 0.7071067811865475f));
}

// ---------------------------------------------------------------------------
// Weight transpose + cast: W (K x N fp32, row-major) -> Wt (N x K bf16)
// ---------------------------------------------------------------------------
__global__ __launch_bounds__(256) void transpose_cast(
    const float* __restrict__ w, short* __restrict__ wt, int K, int N) {
  int idx = blockIdx.x * 256 + threadIdx.x;
  if (idx >= K * N) return;
  int k = idx / N;
  int n = idx - k * N;
  wt[(size_t)n * K + k] = f2bf(w[idx]);
}

// ---------------------------------------------------------------------------
// LayerNorm (one wave per token).  IN = float or short(bf16).
// windowed=1: also apply cyclic shift (-3,-3) and window partition.
// ---------------------------------------------------------------------------
template <typename IN>
__global__ __launch_bounds__(256) void ln_kernel(
    const IN* __restrict__ x, const float* __restrict__ g,
    const float* __restrict__ b, short* __restrict__ y, int windowed) {
  int token = blockIdx.x * 4 + (threadIdx.x >> 6);
  int lane = threadIdx.x & 63;
  size_t src;
  if (windowed) {
    int bw = token / 49;
    int tt = token - bw * 49;
    int bb = bw >> 6, w = bw & 63;
    int hs = (w >> 3) * 7 + tt / 7 + 3; if (hs >= 56) hs -= 56;
    int ws = (w & 7) * 7 + (tt % 7) + 3; if (ws >= 56) ws -= 56;
    src = (size_t)(bb * NIMG + hs * 56 + ws) * C_DIM;
  } else {
    src = (size_t)token * C_DIM;
  }
  const IN* xr = x + src;
  float v[6];
  float s = 0.f;
#pragma unroll
  for (int i = 0; i < 6; ++i) {
    if constexpr (sizeof(IN) == 4) v[i] = (float)xr[lane + i * 64];
    else v[i] = bf2f((short)xr[lane + i * 64]);
    s += v[i];
  }
#pragma unroll
  for (int m = 1; m < 64; m <<= 1) s += __shfl_xor(s, m);
  float mu = s * (1.0f / 384.0f);
  float var = 0.f;
#pragma unroll
  for (int i = 0; i < 6; ++i) { float d = v[i] - mu; var += d * d; }
#pragma unroll
  for (int m = 1; m < 64; m <<= 1) var += __shfl_xor(var, m);
  float rstd = rsqrtf(var * (1.0f / 384.0f) + 1e-5f);
  short* yr = y + (size_t)token * C_DIM;
#pragma unroll
  for (int i = 0; i < 6; ++i) {
    int c = lane + i * 64;
    yr[c] = f2bf((v[i] - mu) * rstd * g[c] + b[c]);
  }
}

// ---------------------------------------------------------------------------
// GEMM: C(M,N) = A(M,K) * Bt(N,K)^T, bf16 in, fp32 acc.  128x128 tile, BK=64,
// 4 waves each 64x64 (4x4 of 16x16x32 MFMA).  global_load_lds staging with
// XOR-8 chunk swizzle (2-way max LDS conflicts).
//
// 2-deep pipelined double-buffered K-loop (T3/T4 minimum 2-phase):
//   prologue stage(buf0); per iter: stage(buf^1, t+1) -> s_waitcnt vmcnt(8)
//   (my 8 oldest loads = tile t done; tile t+1's 8 stay in flight across the
//   barrier) -> s_barrier -> ds_read+MFMA (setprio 1) -> s_barrier.
//   Raw s_barrier (NOT __syncthreads: that drains vmcnt(0) and kills overlap).
//   LDS 64 KB -> 2 blocks/CU.
//
// Grid: 1D, XCD-bijective chunked, n-fastest decode: swz=(wg&7)*(nwg/8)+wg>>3,
//   mb=swz/nby, nb=swz%nby.  nwg always %8==0 (392=49*8) and chunk = 49 whole
//   m-panels: the nby N-siblings of an A-panel co-reside on one XCD -> A-panel
//   read from HBM once, siblings hit that XCD's L2.
//
// EPI: 0 plain bf16 store; 1 proj: +bias +x(fp32) residual, window-reverse
// scatter -> bf16 x1; 2 bias+gelu -> bf16; 3 bias+gelu+bf16 resid -> fp32 out.
// ---------------------------------------------------------------------------
template <int EPI>
__global__ __launch_bounds__(256, 2) void gemm_kernel(
    const short* __restrict__ A, const short* __restrict__ Bt,
    void* __restrict__ Out, const float* __restrict__ bias,
    const void* __restrict__ resid, int M, int N, int K, int nby) {
  __shared__ __align__(16) short lds[2][128 * 64 * 2];
  const int t = threadIdx.x;
  const int wave = t >> 6, lane = t & 63;
  const int lrow = lane & 15, quad = lane >> 4;
  const int wm = wave & 1, wn = wave >> 1;

  const int wg = (int)blockIdx.x;
  const int swz = (wg & 7) * ((int)gridDim.x >> 3) + (wg >> 3);
  const int mb = swz / nby;
  const int nb = swz - mb * nby;
  const int m0 = mb * 128, n0 = nb * 128;

  f32x4 acc[4][4] = {};

  const int srow = t >> 3;  // 0..31
  const int spos = t & 7;   // chunk slot within 64-elem row

  const int nt = K >> 6;

  auto stage = [&](int buf, int k0) {
    short* la = &lds[buf][0];
    short* lb = la + 128 * 64;
#pragma unroll
    for (int i = 0; i < 4; ++i) {
      int row = i * 32 + srow;
      int ca = spos ^ (row & 7);  // store global chunk ca at slot spos
      async_copy16(A + (size_t)(m0 + row) * K + k0 + ca * 8,
                   la + (i * 32 + wave * 8) * 64);
      async_copy16(Bt + (size_t)(n0 + row) * K + k0 + ca * 8,
                   lb + (i * 32 + wave * 8) * 64);
    }
  };

  stage(0, 0);  // prologue: 8 loads/wave in flight

  for (int kt = 0; kt < nt; ++kt) {
    __builtin_amdgcn_sched_barrier(0);
    if (kt + 1 < nt) {
      stage((kt + 1) & 1, (kt + 1) * 64);             // 8 more loads in flight
      asm volatile("s_waitcnt vmcnt(8)" ::: "memory"); // tile kt's 8 landed
    } else {
      asm volatile("s_waitcnt vmcnt(0)" ::: "memory"); // last tile: full drain
    }
    __builtin_amdgcn_s_barrier();   // all waves' tile-kt data in LDS
    __builtin_amdgcn_sched_barrier(0);

    short* ldsA = &lds[kt & 1][0];
    short* ldsB = ldsA + 128 * 64;
#pragma unroll
    for (int ks = 0; ks < 2; ++ks) {
      const int cb = ks * 4;
      bf16x8 af[4], bfr[4];
#pragma unroll
      for (int i = 0; i < 4; ++i) {
        int ra = wm * 64 + i * 16 + lrow;
        af[i] = *(const bf16x8*)(ldsA + ra * 64 + (((cb + quad) ^ (ra & 7)) * 8));
        int rb = wn * 64 + i * 16 + lrow;
        bfr[i] = *(const bf16x8*)(ldsB + rb * 64 + (((cb + quad) ^ (rb & 7)) * 8));
      }
      __builtin_amdgcn_s_setprio(1);
#pragma unroll
      for (int i = 0; i < 4; ++i)
#pragma unroll
        for (int j = 0; j < 4; ++j)
          acc[i][j] = __builtin_amdgcn_mfma_f32_16x16x32_bf16(af[i], bfr[j],
                                                              acc[i][j], 0, 0, 0);
      __builtin_amdgcn_s_setprio(0);
    }
    __builtin_amdgcn_sched_barrier(0);
    __builtin_amdgcn_s_barrier();   // all waves done reading buf[kt&1]
  }

#pragma unroll
  for (int i = 0; i < 4; ++i) {
#pragma unroll
    for (int r = 0; r < 4; ++r) {
      int row = m0 + wm * 64 + i * 16 + quad * 4 + r;
      if (EPI == 1) {
        int bw = row / 49;
        int tt = row - bw * 49;
        int bb = bw >> 6, w = bw & 63;
        int nimg = ((w >> 3) * 7 + tt / 7) * 56 + (w & 7) * 7 + (tt % 7);
        size_t obase = ((size_t)(bb * NIMG + nimg)) * C_DIM;
#pragma unroll
        for (int j = 0; j < 4; ++j) {
          int col = n0 + wn * 64 + j * 16 + lrow;
          size_t oi = obase + col;
          ((short*)Out)[oi] =
              f2bf(acc[i][j][r] + bias[col] + ((const float*)resid)[oi]);
        }
      } else {
#pragma unroll
        for (int j = 0; j < 4; ++j) {
          int col = n0 + wn * 64 + j * 16 + lrow;
          float v = acc[i][j][r];
          if (EPI == 0) {
            ((short*)Out)[(size_t)row * N + col] = f2bf(v);
          } else if (EPI == 2) {
            ((short*)Out)[(size_t)row * N + col] = f2bf(gelu_exact(v + bias[col]));
          } else {  // EPI == 3
            size_t oi = (size_t)row * C_DIM + col;
            ((float*)Out)[oi] =
                bf2f(((const short*)resid)[oi]) + gelu_exact(v + bias[col]);
          }
        }
      }
    }
  }
}

// ---------------------------------------------------------------------------
// Attention: one wave per (window, head).  qkv layout: row (bw*49+t), 1152
// cols = [Q 384 | K 384 | V 384], head h at col h*32.
// ---------------------------------------------------------------------------
__global__ __launch_bounds__(256) void attn_kernel(
    const short* __restrict__ qkv, short* __restrict__ o) {
  __shared__ __align__(16) short plds[4][64 * 72];  // +8 pad per row: no conflicts
  const int wavei = threadIdx.x >> 6;
  const int lane = threadIdx.x & 63;
  const int gw = blockIdx.x * 4 + wavei;       // 0..12287
  const int bw = gw / 12;
  const int h = gw - bw * 12;
  const int w = bw & 63;
  const int lrow = lane & 15, quad = lane >> 4;
  const short* base = qkv + (size_t)bw * 49 * 1152 + h * 32;

  // ---- S = Q K^T ----
  bf16x8 qf[4], kf[4];
#pragma unroll
  for (int i = 0; i < 4; ++i) {
    int tq = i * 16 + lrow;  // rows >=49 read slack (in-bounds), masked later
    const short* p = base + (size_t)tq * 1152 + quad * 8;
    qf[i] = *(const bf16x8*)p;
    kf[i] = *(const bf16x8*)(p + 384);
  }
  f32x4 sa[4][4] = {};
#pragma unroll
  for (int i = 0; i < 4; ++i)
#pragma unroll
    for (int j = 0; j < 4; ++j)
      sa[i][j] = __builtin_amdgcn_mfma_f32_16x16x32_bf16(qf[i], kf[j], sa[i][j], 0, 0, 0);

  // ---- region id for shift-window mask (this lane's token = lane) ----
  int tl = lane < 49 ? lane : 0;
  int rr = tl / 7, cc = tl - rr * 7;
  int hs = (w >> 3) * 7 + rr;
  int ws = (w & 7) * 7 + cc;
  int id = (hs < 49 ? 0 : (hs < 53 ? 3 : 6)) + (ws < 49 ? 0 : (ws < 53 ? 1 : 2));

  int idn[4], idm[4][4];
#pragma unroll
  for (int j = 0; j < 4; ++j) idn[j] = __shfl(id, j * 16 + lrow);
#pragma unroll
  for (int i = 0; i < 4; ++i)
#pragma unroll
    for (int r = 0; r < 4; ++r) idm[i][r] = __shfl(id, i * 16 + quad * 4 + r);

#pragma unroll
  for (int i = 0; i < 4; ++i)
#pragma unroll
    for (int j = 0; j < 4; ++j)
#pragma unroll
      for (int r = 0; r < 4; ++r) {
        float v = sa[i][j][r] * QK_SCALE + (idm[i][r] == idn[j] ? 0.f : -100.f);
        sa[i][j][r] = (j * 16 + lrow < 49) ? v : -1e30f;
      }

  // ---- softmax over rows (16-lane groups) ----
#pragma unroll
  for (int i = 0; i < 4; ++i)
#pragma unroll
    for (int r = 0; r < 4; ++r) {
      float mx = -1e30f;
#pragma unroll
      for (int j = 0; j < 4; ++j) mx = fmaxf(mx, sa[i][j][r]);
#pragma unroll
      for (int m = 1; m < 16; m <<= 1) mx = fmaxf(mx, __shfl_xor(mx, m));
      float sum = 0.f;
#pragma unroll
      for (int j = 0; j < 4; ++j) {
        float e = exp2f((sa[i][j][r] - mx) * 1.44269504f);
        sa[i][j][r] = e;
        sum += e;
      }
#pragma unroll
      for (int m = 1; m < 16; m <<= 1) sum += __shfl_xor(sum, m);
      float inv = 1.0f / sum;
#pragma unroll
      for (int j = 0; j < 4; ++j) sa[i][j][r] *= inv;
    }

  // ---- P -> LDS (C-layout -> row-major bf16, A-operand readable) ----
  short* pw = plds[wavei];
#pragma unroll
  for (int i = 0; i < 4; ++i)
#pragma unroll
    for (int r = 0; r < 4; ++r)
#pragma unroll
      for (int j = 0; j < 4; ++j)
        pw[(i * 16 + quad * 4 + r) * 72 + j * 16 + lrow] = f2bf(sa[i][j][r]);

  // ---- O = P V ----
  f32x4 oa[4][2] = {};
#pragma unroll
  for (int kk = 0; kk < 2; ++kk) {
    bf16x8 vf[2];
#pragma unroll
    for (int j2 = 0; j2 < 2; ++j2) {
#pragma unroll
      for (int jj = 0; jj < 8; ++jj) {
        int n = kk * 32 + quad * 8 + jj;
        vf[j2][jj] = (n < 49)
            ? base[768 + (size_t)n * 1152 + j2 * 16 + lrow]
            : (short)0;
      }
    }
#pragma unroll
    for (int i = 0; i < 4; ++i) {
      bf16x8 pf = *(const bf16x8*)(pw + (i * 16 + lrow) * 72 + kk * 32 + quad * 8);
#pragma unroll
      for (int j2 = 0; j2 < 2; ++j2)
        oa[i][j2] = __builtin_amdgcn_mfma_f32_16x16x32_bf16(pf, vf[j2], oa[i][j2], 0, 0, 0);
    }
  }

#pragma unroll
  for (int i = 0; i < 4; ++i)
#pragma unroll
    for (int j2 = 0; j2 < 2; ++j2)
#pragma unroll
      for (int r = 0; r < 4; ++r) {
        int m = i * 16 + quad * 4 + r;
        if (m < 49)
          o[((size_t)bw * 49 + m) * 384 + h * 32 + j2 * 16 + lrow] = f2bf(oa[i][j2][r]);
      }
}

// ---------------------------------------------------------------------------
extern "C" void kernel_launch(void* const* d_in, const int* in_sizes, int n_in,
                              void* d_out, int out_size, void* d_ws, size_t ws_size,
                              hipStream_t stream) {
  const float* x      = (const float*)d_in[0];
  const float* ln1_g  = (const float*)d_in[1];
  const float* ln1_b  = (const float*)d_in[2];
  const float* qkv_w  = (const float*)d_in[3];
  const float* proj_w = (const float*)d_in[4];
  const float* proj_b = (const float*)d_in[5];
  const float* ln2_g  = (const float*)d_in[6];
  const float* ln2_b  = (const float*)d_in[7];
  const float* fc1_w  = (const float*)d_in[8];
  const float* fc1_b  = (const float*)d_in[9];
  const float* fc2_w  = (const float*)d_in[10];
  const float* fc2_b  = (const float*)d_in[11];
  float* out = (float*)d_out;

  char* ws = (char*)d_ws;
  auto alloc = [&](size_t bytes) {
    char* p = ws;
    ws += (bytes + 255) & ~(size_t)255;
    return p;
  };
  short* qkv_wT  = (short*)alloc((size_t)1152 * 384 * 2);
  short* proj_wT = (short*)alloc((size_t)384 * 384 * 2);
  short* fc1_wT  = (short*)alloc((size_t)1536 * 384 * 2);
  short* fc2_wT  = (short*)alloc((size_t)384 * 1536 * 2);
  short* bufA    = (short*)alloc((size_t)MROWS * 384 * 2);   // y_win / o / m
  short* x1      = (short*)alloc((size_t)MROWS * 384 * 2);   // bf16 residual
  short* bufB    = (short*)alloc((size_t)MROWS * 1536 * 2);  // qkv / fc1 act

  // weights -> bf16 transposed
  transpose_cast<<<(384 * 1152) / 256, 256, 0, stream>>>(qkv_w, qkv_wT, 384, 1152);
  transpose_cast<<<(384 * 384) / 256, 256, 0, stream>>>(proj_w, proj_wT, 384, 384);
  transpose_cast<<<(384 * 1536) / 256, 256, 0, stream>>>(fc1_w, fc1_wT, 384, 1536);
  transpose_cast<<<(1536 * 384) / 256, 256, 0, stream>>>(fc2_w, fc2_wT, 1536, 384);

  // LN1 + shift + window partition
  ln_kernel<float><<<MROWS / 4, 256, 0, stream>>>(x, ln1_g, ln1_b, bufA, 1);

  // qkv = y @ qkv_w  (50176 x 1152), grid 392*9 (1D, XCD-chunked)
  gemm_kernel<0><<<392 * 9, 256, 0, stream>>>(bufA, qkv_wT, bufB, nullptr,
                                              nullptr, MROWS, 1152, 384, 9);

  // attention -> o (windowed layout) into bufA
  attn_kernel<<<3072, 256, 0, stream>>>(bufB, bufA);

  // x1 = x + (o @ proj_w + proj_b) window-reversed  (bf16 out)
  gemm_kernel<1><<<392 * 3, 256, 0, stream>>>(bufA, proj_wT, x1, proj_b,
                                              x, MROWS, 384, 384, 3);

  // m = LN2(x1)
  ln_kernel<short><<<MROWS / 4, 256, 0, stream>>>(x1, ln2_g, ln2_b, bufA, 0);

  // a1 = gelu(m @ fc1_w + fc1_b)  (50176 x 1536)
  gemm_kernel<2><<<392 * 12, 256, 0, stream>>>(bufA, fc1_wT, bufB, fc1_b,
                                               nullptr, MROWS, 1536, 384, 12);

  // out = x1 + gelu(a1 @ fc2_w + fc2_b)
  gemm_kernel<3><<<392 * 3, 256, 0, stream>>>(bufB, fc2_wT, out, fc2_b,
                                              x1, MROWS, 384, 1536, 3);
}

// Round 2
// 525.781 us; speedup vs baseline: 1.0893x; 1.0893x over previous
//
#include <hip/hip_runtime.h>
#include <hip/hip_bf16.h>
#include <cstdint>
#include <cstddef>

#define C_DIM   384
#define NIMG    3136      // 56*56
#define MROWS   50176     // 16*3136 tokens
#define QK_SCALE 0.17677669529663687f  // 32^-0.5

using bf16x8 = __attribute__((ext_vector_type(8))) short;   // 8 bf16 in 4 VGPRs
using f32x4  = __attribute__((ext_vector_type(4))) float;

__device__ __forceinline__ short f2bf(float f) {
  union { float f; uint32_t u; } v; v.f = f;
  uint32_t r = (v.u + 0x7fffu + ((v.u >> 16) & 1u)) >> 16;  // RNE
  return (short)(uint16_t)r;
}

__device__ __forceinline__ float bf2f(short s) {
  union { uint32_t u; float f; } v; v.u = ((uint32_t)(uint16_t)s) << 16;
  return v.f;
}

__device__ __forceinline__ void async_copy16(const void* g, void* l) {
  __builtin_amdgcn_global_load_lds(
      (const __attribute__((address_space(1))) void*)g,
      (__attribute__((address_space(3))) void*)l, 16, 0, 0);
}

// Branch-free gelu: A&S 7.1.26 erf (max abs err 1.5e-7), rcp+exp2+5 FMA.
// Replaces ocml erff whose if-converted expf path costs ~40+ VALU ops/elem.
__device__ __forceinline__ float gelu_fast(float x) {
  float z = fabsf(x) * 0.7071067811865476f;
  float t = __builtin_amdgcn_rcpf(fmaf(0.3275911f, z, 1.0f));
  float p = t * fmaf(t, fmaf(t, fmaf(t, fmaf(t, 1.061405429f, -1.453152027f),
                                     1.421413741f), -0.284496736f),
                     0.254829592f);
  float e = p * exp2f(z * z * -1.4426950408889634f);  // poly * exp(-z^2)
  float phi2 = (x >= 0.0f) ? (2.0f - e) : e;          // 1 + erf(x/sqrt2)
  return 0.5f * x * phi2;
}

// ---------------------------------------------------------------------------
// Weight transpose + cast: W (K x N fp32, row-major) -> Wt (N x K bf16)
// ---------------------------------------------------------------------------
__global__ __launch_bounds__(256) void transpose_cast(
    const float* __restrict__ w, short* __restrict__ wt, int K, int N) {
  int idx = blockIdx.x * 256 + threadIdx.x;
  if (idx >= K * N) return;
  int k = idx / N;
  int n = idx - k * N;
  wt[(size_t)n * K + k] = f2bf(w[idx]);
}

// ---------------------------------------------------------------------------
// LayerNorm (one wave per token).  IN = float or short(bf16).
// windowed=1: also apply cyclic shift (-3,-3) and window partition.
// ---------------------------------------------------------------------------
template <typename IN>
__global__ __launch_bounds__(256) void ln_kernel(
    const IN* __restrict__ x, const float* __restrict__ g,
    const float* __restrict__ b, short* __restrict__ y, int windowed) {
  int token = blockIdx.x * 4 + (threadIdx.x >> 6);
  int lane = threadIdx.x & 63;
  size_t src;
  if (windowed) {
    int bw = token / 49;
    int tt = token - bw * 49;
    int bb = bw >> 6, w = bw & 63;
    int hs = (w >> 3) * 7 + tt / 7 + 3; if (hs >= 56) hs -= 56;
    int ws = (w & 7) * 7 + (tt % 7) + 3; if (ws >= 56) ws -= 56;
    src = (size_t)(bb * NIMG + hs * 56 + ws) * C_DIM;
  } else {
    src = (size_t)token * C_DIM;
  }
  const IN* xr = x + src;
  float v[6];
  float s = 0.f;
#pragma unroll
  for (int i = 0; i < 6; ++i) {
    if constexpr (sizeof(IN) == 4) v[i] = (float)xr[lane + i * 64];
    else v[i] = bf2f((short)xr[lane + i * 64]);
    s += v[i];
  }
#pragma unroll
  for (int m = 1; m < 64; m <<= 1) s += __shfl_xor(s, m);
  float mu = s * (1.0f / 384.0f);
  float var = 0.f;
#pragma unroll
  for (int i = 0; i < 6; ++i) { float d = v[i] - mu; var += d * d; }
#pragma unroll
  for (int m = 1; m < 64; m <<= 1) var += __shfl_xor(var, m);
  float rstd = rsqrtf(var * (1.0f / 384.0f) + 1e-5f);
  short* yr = y + (size_t)token * C_DIM;
#pragma unroll
  for (int i = 0; i < 6; ++i) {
    int c = lane + i * 64;
    yr[c] = f2bf((v[i] - mu) * rstd * g[c] + b[c]);
  }
}

// ---------------------------------------------------------------------------
// GEMM: C(M,N) = A(M,K) * Bt(N,K)^T, bf16 in, fp32 acc.  128x128 tile, BK=64,
// 4 waves each 64x64 (4x4 of 16x16x32 MFMA).  global_load_lds staging with
// XOR-8 chunk swizzle (2-way max LDS conflicts).
//
// PIPE=0 (short-K, nt<=6): single 32 KB buffer, __syncthreads loop,
//   4 blocks/CU -- occupancy hides the epilogue; depth-2 pipelining can't
//   amortize over 6 K-steps.
// PIPE=1 (long-K): 2-deep double-buffered pipeline, raw s_barrier +
//   counted s_waitcnt vmcnt(8) (next tile's 8 loads stay in flight across
//   the barrier), setprio(1) around MFMA.  64 KB LDS -> 2 blocks/CU.
//
// Grid: 1D, XCD-bijective chunked, n-fastest decode: swz=(wg&7)*(nwg/8)+wg>>3,
//   mb=swz/nby, nb=swz%nby.  nwg %8==0 (392=49*8): the nby N-siblings of an
//   A-panel co-reside on one XCD -> A-panel fetched from HBM once.
//
// EPI: 0 plain bf16 store; 1 proj: +bias +x(fp32) residual, window-reverse
// scatter -> bf16 x1; 2 bias+gelu -> bf16; 3 bias+gelu+bf16 resid -> fp32 out.
// ---------------------------------------------------------------------------
template <int EPI, int PIPE>
__global__ __launch_bounds__(256, PIPE ? 2 : 4) void gemm_kernel(
    const short* __restrict__ A, const short* __restrict__ Bt,
    void* __restrict__ Out, const float* __restrict__ bias,
    const void* __restrict__ resid, int M, int N, int K, int nby) {
  constexpr int NBUF = PIPE ? 2 : 1;
  __shared__ __align__(16) short lds[NBUF][128 * 64 * 2];
  const int t = threadIdx.x;
  const int wave = t >> 6, lane = t & 63;
  const int lrow = lane & 15, quad = lane >> 4;
  const int wm = wave & 1, wn = wave >> 1;

  const int wg = (int)blockIdx.x;
  const int swz = (wg & 7) * ((int)gridDim.x >> 3) + (wg >> 3);
  const int mb = swz / nby;
  const int nb = swz - mb * nby;
  const int m0 = mb * 128, n0 = nb * 128;

  f32x4 acc[4][4] = {};

  const int srow = t >> 3;  // 0..31
  const int spos = t & 7;   // chunk slot within 64-elem row

  const int nt = K >> 6;

  auto stage = [&](int buf, int k0) {
    short* la = &lds[buf][0];
    short* lb = la + 128 * 64;
#pragma unroll
    for (int i = 0; i < 4; ++i) {
      int row = i * 32 + srow;
      int ca = spos ^ (row & 7);  // store global chunk ca at slot spos
      async_copy16(A + (size_t)(m0 + row) * K + k0 + ca * 8,
                   la + (i * 32 + wave * 8) * 64);
      async_copy16(Bt + (size_t)(n0 + row) * K + k0 + ca * 8,
                   lb + (i * 32 + wave * 8) * 64);
    }
  };

  auto compute = [&](int buf) {
    short* ldsA = &lds[buf][0];
    short* ldsB = ldsA + 128 * 64;
#pragma unroll
    for (int ks = 0; ks < 2; ++ks) {
      const int cb = ks * 4;
      bf16x8 af[4], bfr[4];
#pragma unroll
      for (int i = 0; i < 4; ++i) {
        int ra = wm * 64 + i * 16 + lrow;
        af[i] = *(const bf16x8*)(ldsA + ra * 64 + (((cb + quad) ^ (ra & 7)) * 8));
        int rb = wn * 64 + i * 16 + lrow;
        bfr[i] = *(const bf16x8*)(ldsB + rb * 64 + (((cb + quad) ^ (rb & 7)) * 8));
      }
      if (PIPE) __builtin_amdgcn_s_setprio(1);
#pragma unroll
      for (int i = 0; i < 4; ++i)
#pragma unroll
        for (int j = 0; j < 4; ++j)
          acc[i][j] = __builtin_amdgcn_mfma_f32_16x16x32_bf16(af[i], bfr[j],
                                                              acc[i][j], 0, 0, 0);
      if (PIPE) __builtin_amdgcn_s_setprio(0);
    }
  };

  if constexpr (PIPE == 0) {
    for (int kt = 0; kt < nt; ++kt) {
      __syncthreads();
      stage(0, kt * 64);
      __syncthreads();
      compute(0);
    }
  } else {
    stage(0, 0);  // prologue: 8 loads/wave in flight
    for (int kt = 0; kt < nt; ++kt) {
      __builtin_amdgcn_sched_barrier(0);
      if (kt + 1 < nt) {
        stage((kt + 1) & 1, (kt + 1) * 64);             // 8 more in flight
        asm volatile("s_waitcnt vmcnt(8)" ::: "memory"); // tile kt landed
      } else {
        asm volatile("s_waitcnt vmcnt(0)" ::: "memory"); // last: full drain
      }
      __builtin_amdgcn_s_barrier();   // all waves' tile-kt data in LDS
      __builtin_amdgcn_sched_barrier(0);
      compute(kt & 1);
      __builtin_amdgcn_sched_barrier(0);
      __builtin_amdgcn_s_barrier();   // all waves done reading buf[kt&1]
    }
  }

#pragma unroll
  for (int i = 0; i < 4; ++i) {
#pragma unroll
    for (int r = 0; r < 4; ++r) {
      int row = m0 + wm * 64 + i * 16 + quad * 4 + r;
      if (EPI == 1) {
        int bw = row / 49;
        int tt = row - bw * 49;
        int bb = bw >> 6, w = bw & 63;
        int nimg = ((w >> 3) * 7 + tt / 7) * 56 + (w & 7) * 7 + (tt % 7);
        size_t obase = ((size_t)(bb * NIMG + nimg)) * C_DIM;
#pragma unroll
        for (int j = 0; j < 4; ++j) {
          int col = n0 + wn * 64 + j * 16 + lrow;
          size_t oi = obase + col;
          ((short*)Out)[oi] =
              f2bf(acc[i][j][r] + bias[col] + ((const float*)resid)[oi]);
        }
      } else {
#pragma unroll
        for (int j = 0; j < 4; ++j) {
          int col = n0 + wn * 64 + j * 16 + lrow;
          float v = acc[i][j][r];
          if (EPI == 0) {
            ((short*)Out)[(size_t)row * N + col] = f2bf(v);
          } else if (EPI == 2) {
            ((short*)Out)[(size_t)row * N + col] = f2bf(gelu_fast(v + bias[col]));
          } else {  // EPI == 3
            size_t oi = (size_t)row * C_DIM + col;
            ((float*)Out)[oi] =
                bf2f(((const short*)resid)[oi]) + gelu_fast(v + bias[col]);
          }
        }
      }
    }
  }
}

// ---------------------------------------------------------------------------
// Attention: one wave per (window, head).  qkv layout: row (bw*49+t), 1152
// cols = [Q 384 | K 384 | V 384], head h at col h*32.
// ---------------------------------------------------------------------------
__global__ __launch_bounds__(256) void attn_kernel(
    const short* __restrict__ qkv, short* __restrict__ o) {
  __shared__ __align__(16) short plds[4][64 * 72];  // +8 pad per row: no conflicts
  const int wavei = threadIdx.x >> 6;
  const int lane = threadIdx.x & 63;
  const int gw = blockIdx.x * 4 + wavei;       // 0..12287
  const int bw = gw / 12;
  const int h = gw - bw * 12;
  const int w = bw & 63;
  const int lrow = lane & 15, quad = lane >> 4;
  const short* base = qkv + (size_t)bw * 49 * 1152 + h * 32;

  // ---- S = Q K^T ----
  bf16x8 qf[4], kf[4];
#pragma unroll
  for (int i = 0; i < 4; ++i) {
    int tq = i * 16 + lrow;  // rows >=49 read slack (in-bounds), masked later
    const short* p = base + (size_t)tq * 1152 + quad * 8;
    qf[i] = *(const bf16x8*)p;
    kf[i] = *(const bf16x8*)(p + 384);
  }
  f32x4 sa[4][4] = {};
#pragma unroll
  for (int i = 0; i < 4; ++i)
#pragma unroll
    for (int j = 0; j < 4; ++j)
      sa[i][j] = __builtin_amdgcn_mfma_f32_16x16x32_bf16(qf[i], kf[j], sa[i][j], 0, 0, 0);

  // ---- region id for shift-window mask (this lane's token = lane) ----
  int tl = lane < 49 ? lane : 0;
  int rr = tl / 7, cc = tl - rr * 7;
  int hs = (w >> 3) * 7 + rr;
  int ws = (w & 7) * 7 + cc;
  int id = (hs < 49 ? 0 : (hs < 53 ? 3 : 6)) + (ws < 49 ? 0 : (ws < 53 ? 1 : 2));

  int idn[4], idm[4][4];
#pragma unroll
  for (int j = 0; j < 4; ++j) idn[j] = __shfl(id, j * 16 + lrow);
#pragma unroll
  for (int i = 0; i < 4; ++i)
#pragma unroll
    for (int r = 0; r < 4; ++r) idm[i][r] = __shfl(id, i * 16 + quad * 4 + r);

#pragma unroll
  for (int i = 0; i < 4; ++i)
#pragma unroll
    for (int j = 0; j < 4; ++j)
#pragma unroll
      for (int r = 0; r < 4; ++r) {
        float v = sa[i][j][r] * QK_SCALE + (idm[i][r] == idn[j] ? 0.f : -100.f);
        sa[i][j][r] = (j * 16 + lrow < 49) ? v : -1e30f;
      }

  // ---- softmax over rows (16-lane groups) ----
#pragma unroll
  for (int i = 0; i < 4; ++i)
#pragma unroll
    for (int r = 0; r < 4; ++r) {
      float mx = -1e30f;
#pragma unroll
      for (int j = 0; j < 4; ++j) mx = fmaxf(mx, sa[i][j][r]);
#pragma unroll
      for (int m = 1; m < 16; m <<= 1) mx = fmaxf(mx, __shfl_xor(mx, m));
      float sum = 0.f;
#pragma unroll
      for (int j = 0; j < 4; ++j) {
        float e = exp2f((sa[i][j][r] - mx) * 1.44269504f);
        sa[i][j][r] = e;
        sum += e;
      }
#pragma unroll
      for (int m = 1; m < 16; m <<= 1) sum += __shfl_xor(sum, m);
      float inv = 1.0f / sum;
#pragma unroll
      for (int j = 0; j < 4; ++j) sa[i][j][r] *= inv;
    }

  // ---- P -> LDS (C-layout -> row-major bf16, A-operand readable) ----
  short* pw = plds[wavei];
#pragma unroll
  for (int i = 0; i < 4; ++i)
#pragma unroll
    for (int r = 0; r < 4; ++r)
#pragma unroll
      for (int j = 0; j < 4; ++j)
        pw[(i * 16 + quad * 4 + r) * 72 + j * 16 + lrow] = f2bf(sa[i][j][r]);

  // ---- O = P V ----
  f32x4 oa[4][2] = {};
#pragma unroll
  for (int kk = 0; kk < 2; ++kk) {
    bf16x8 vf[2];
#pragma unroll
    for (int j2 = 0; j2 < 2; ++j2) {
#pragma unroll
      for (int jj = 0; jj < 8; ++jj) {
        int n = kk * 32 + quad * 8 + jj;
        vf[j2][jj] = (n < 49)
            ? base[768 + (size_t)n * 1152 + j2 * 16 + lrow]
            : (short)0;
      }
    }
#pragma unroll
    for (int i = 0; i < 4; ++i) {
      bf16x8 pf = *(const bf16x8*)(pw + (i * 16 + lrow) * 72 + kk * 32 + quad * 8);
#pragma unroll
      for (int j2 = 0; j2 < 2; ++j2)
        oa[i][j2] = __builtin_amdgcn_mfma_f32_16x16x32_bf16(pf, vf[j2], oa[i][j2], 0, 0, 0);
    }
  }

#pragma unroll
  for (int i = 0; i < 4; ++i)
#pragma unroll
    for (int j2 = 0; j2 < 2; ++j2)
#pragma unroll
      for (int r = 0; r < 4; ++r) {
        int m = i * 16 + quad * 4 + r;
        if (m < 49)
          o[((size_t)bw * 49 + m) * 384 + h * 32 + j2 * 16 + lrow] = f2bf(oa[i][j2][r]);
      }
}

// ---------------------------------------------------------------------------
extern "C" void kernel_launch(void* const* d_in, const int* in_sizes, int n_in,
                              void* d_out, int out_size, void* d_ws, size_t ws_size,
                              hipStream_t stream) {
  const float* x      = (const float*)d_in[0];
  const float* ln1_g  = (const float*)d_in[1];
  const float* ln1_b  = (const float*)d_in[2];
  const float* qkv_w  = (const float*)d_in[3];
  const float* proj_w = (const float*)d_in[4];
  const float* proj_b = (const float*)d_in[5];
  const float* ln2_g  = (const float*)d_in[6];
  const float* ln2_b  = (const float*)d_in[7];
  const float* fc1_w  = (const float*)d_in[8];
  const float* fc1_b  = (const float*)d_in[9];
  const float* fc2_w  = (const float*)d_in[10];
  const float* fc2_b  = (const float*)d_in[11];
  float* out = (float*)d_out;

  char* ws = (char*)d_ws;
  auto alloc = [&](size_t bytes) {
    char* p = ws;
    ws += (bytes + 255) & ~(size_t)255;
    return p;
  };
  short* qkv_wT  = (short*)alloc((size_t)1152 * 384 * 2);
  short* proj_wT = (short*)alloc((size_t)384 * 384 * 2);
  short* fc1_wT  = (short*)alloc((size_t)1536 * 384 * 2);
  short* fc2_wT  = (short*)alloc((size_t)384 * 1536 * 2);
  short* bufA    = (short*)alloc((size_t)MROWS * 384 * 2);   // y_win / o / m
  short* x1      = (short*)alloc((size_t)MROWS * 384 * 2);   // bf16 residual
  short* bufB    = (short*)alloc((size_t)MROWS * 1536 * 2);  // qkv / fc1 act

  // weights -> bf16 transposed
  transpose_cast<<<(384 * 1152) / 256, 256, 0, stream>>>(qkv_w, qkv_wT, 384, 1152);
  transpose_cast<<<(384 * 384) / 256, 256, 0, stream>>>(proj_w, proj_wT, 384, 384);
  transpose_cast<<<(384 * 1536) / 256, 256, 0, stream>>>(fc1_w, fc1_wT, 384, 1536);
  transpose_cast<<<(1536 * 384) / 256, 256, 0, stream>>>(fc2_w, fc2_wT, 1536, 384);

  // LN1 + shift + window partition
  ln_kernel<float><<<MROWS / 4, 256, 0, stream>>>(x, ln1_g, ln1_b, bufA, 1);

  // qkv = y @ qkv_w  (50176 x 1152), K=384 -> PIPE=0
  gemm_kernel<0, 0><<<392 * 9, 256, 0, stream>>>(bufA, qkv_wT, bufB, nullptr,
                                                 nullptr, MROWS, 1152, 384, 9);

  // attention -> o (windowed layout) into bufA
  attn_kernel<<<3072, 256, 0, stream>>>(bufB, bufA);

  // x1 = x + (o @ proj_w + proj_b) window-reversed  (bf16 out), K=384 -> PIPE=0
  gemm_kernel<1, 0><<<392 * 3, 256, 0, stream>>>(bufA, proj_wT, x1, proj_b,
                                                 x, MROWS, 384, 384, 3);

  // m = LN2(x1)
  ln_kernel<short><<<MROWS / 4, 256, 0, stream>>>(x1, ln2_g, ln2_b, bufA, 0);

  // a1 = gelu(m @ fc1_w + fc1_b)  (50176 x 1536), K=384 -> PIPE=0
  gemm_kernel<2, 0><<<392 * 12, 256, 0, stream>>>(bufA, fc1_wT, bufB, fc1_b,
                                                  nullptr, MROWS, 1536, 384, 12);

  // out = x1 + gelu(a1 @ fc2_w + fc2_b), K=1536 -> PIPE=1 pipelined
  gemm_kernel<3, 1><<<392 * 3, 256, 0, stream>>>(bufB, fc2_wT, out, fc2_b,
                                                 x1, MROWS, 384, 1536, 3);
}

// Round 3
// 517.087 us; speedup vs baseline: 1.1076x; 1.0168x over previous
//
#include <hip/hip_runtime.h>
#include <hip/hip_bf16.h>
#include <cstdint>
#include <cstddef>

#define C_DIM   384
#define NIMG    3136      // 56*56
#define MROWS   50176     // 16*3136 tokens
#define QK_SCALE 0.17677669529663687f  // 32^-0.5

using bf16x8 = __attribute__((ext_vector_type(8))) short;   // 8 bf16 in 4 VGPRs
using f32x4  = __attribute__((ext_vector_type(4))) float;

__device__ __forceinline__ short f2bf(float f) {
  union { float f; uint32_t u; } v; v.f = f;
  uint32_t r = (v.u + 0x7fffu + ((v.u >> 16) & 1u)) >> 16;  // RNE
  return (short)(uint16_t)r;
}

__device__ __forceinline__ float bf2f(short s) {
  union { uint32_t u; float f; } v; v.u = ((uint32_t)(uint16_t)s) << 16;
  return v.f;
}

__device__ __forceinline__ void async_copy16(const void* g, void* l) {
  __builtin_amdgcn_global_load_lds(
      (const __attribute__((address_space(1))) void*)g,
      (__attribute__((address_space(3))) void*)l, 16, 0, 0);
}

// tanh-form gelu, 8 VALU ops (1 exp2 + 1 rcp + 6 mul/fma).
// 0.5x(1+tanh(t)) = x*e/(e+1) = x - x/(e+1), e = exp(2t),
// t = x*(sqrt(2/pi) + 0.044715*sqrt(2/pi)*x^2).
// Max |diff| vs exact erf-gelu ~3e-4 (bf16 chain absmax is 0.03 -- safe).
// Saturates cleanly: x>>0 -> e=inf, r=0, gelu=x;  x<<0 -> e=0, r=1, gelu=0.
__device__ __forceinline__ float gelu_fast(float x) {
  float x2 = x * x;
  float u = fmaf(0.0356774081f, x2, 0.7978845608f);
  float e = exp2f(x * u * 2.8853900818f);          // exp(2t)
  float r = __builtin_amdgcn_rcpf(e + 1.0f);
  return fmaf(-x, r, x);
}

// ---------------------------------------------------------------------------
// Weight transpose + cast: W (K x N fp32, row-major) -> Wt (N x K bf16)
// ---------------------------------------------------------------------------
__global__ __launch_bounds__(256) void transpose_cast(
    const float* __restrict__ w, short* __restrict__ wt, int K, int N) {
  int idx = blockIdx.x * 256 + threadIdx.x;
  if (idx >= K * N) return;
  int k = idx / N;
  int n = idx - k * N;
  wt[(size_t)n * K + k] = f2bf(w[idx]);
}

// ---------------------------------------------------------------------------
// LayerNorm (one wave per token).  IN = float or short(bf16).
// windowed=1: also apply cyclic shift (-3,-3) and window partition.
// ---------------------------------------------------------------------------
template <typename IN>
__global__ __launch_bounds__(256) void ln_kernel(
    const IN* __restrict__ x, const float* __restrict__ g,
    const float* __restrict__ b, short* __restrict__ y, int windowed) {
  int token = blockIdx.x * 4 + (threadIdx.x >> 6);
  int lane = threadIdx.x & 63;
  size_t src;
  if (windowed) {
    int bw = token / 49;
    int tt = token - bw * 49;
    int bb = bw >> 6, w = bw & 63;
    int hs = (w >> 3) * 7 + tt / 7 + 3; if (hs >= 56) hs -= 56;
    int ws = (w & 7) * 7 + (tt % 7) + 3; if (ws >= 56) ws -= 56;
    src = (size_t)(bb * NIMG + hs * 56 + ws) * C_DIM;
  } else {
    src = (size_t)token * C_DIM;
  }
  const IN* xr = x + src;
  float v[6];
  float s = 0.f;
#pragma unroll
  for (int i = 0; i < 6; ++i) {
    if constexpr (sizeof(IN) == 4) v[i] = (float)xr[lane + i * 64];
    else v[i] = bf2f((short)xr[lane + i * 64]);
    s += v[i];
  }
#pragma unroll
  for (int m = 1; m < 64; m <<= 1) s += __shfl_xor(s, m);
  float mu = s * (1.0f / 384.0f);
  float var = 0.f;
#pragma unroll
  for (int i = 0; i < 6; ++i) { float d = v[i] - mu; var += d * d; }
#pragma unroll
  for (int m = 1; m < 64; m <<= 1) var += __shfl_xor(var, m);
  float rstd = rsqrtf(var * (1.0f / 384.0f) + 1e-5f);
  short* yr = y + (size_t)token * C_DIM;
#pragma unroll
  for (int i = 0; i < 6; ++i) {
    int c = lane + i * 64;
    yr[c] = f2bf((v[i] - mu) * rstd * g[c] + b[c]);
  }
}

// ---------------------------------------------------------------------------
// Shared epilogue for both GEMM variants.
// EPI: 0 plain bf16 store; 1 proj: +bias +x(fp32) residual, window-reverse
// scatter -> bf16 x1; 2 bias+gelu -> bf16; 3 bias+gelu+bf16 resid -> fp32 out.
// ---------------------------------------------------------------------------
template <int EPI>
__device__ __forceinline__ void gemm_epilogue(
    f32x4 (&acc)[4][4], void* Out, const float* bias, const void* resid,
    int N, int m0, int n0, int wm, int wn, int lrow, int quad) {
#pragma unroll
  for (int i = 0; i < 4; ++i) {
#pragma unroll
    for (int r = 0; r < 4; ++r) {
      int row = m0 + wm * 64 + i * 16 + quad * 4 + r;
      if (EPI == 1) {
        int bw = row / 49;
        int tt = row - bw * 49;
        int bb = bw >> 6, w = bw & 63;
        int nimg = ((w >> 3) * 7 + tt / 7) * 56 + (w & 7) * 7 + (tt % 7);
        size_t obase = ((size_t)(bb * NIMG + nimg)) * C_DIM;
#pragma unroll
        for (int j = 0; j < 4; ++j) {
          int col = n0 + wn * 64 + j * 16 + lrow;
          size_t oi = obase + col;
          ((short*)Out)[oi] =
              f2bf(acc[i][j][r] + bias[col] + ((const float*)resid)[oi]);
        }
      } else {
#pragma unroll
        for (int j = 0; j < 4; ++j) {
          int col = n0 + wn * 64 + j * 16 + lrow;
          float v = acc[i][j][r];
          if (EPI == 0) {
            ((short*)Out)[(size_t)row * N + col] = f2bf(v);
          } else if (EPI == 2) {
            ((short*)Out)[(size_t)row * N + col] = f2bf(gelu_fast(v + bias[col]));
          } else {  // EPI == 3
            size_t oi = (size_t)row * C_DIM + col;
            ((float*)Out)[oi] =
                bf2f(((const short*)resid)[oi]) + gelu_fast(v + bias[col]);
          }
        }
      }
    }
  }
}

// XCD-bijective chunked 1D grid, n-fastest decode (nwg %8 == 0 always:
// 392 = 49*8).  The nby N-siblings of an A-panel co-reside on one XCD.
__device__ __forceinline__ void grid_decode(int nby, int& m0, int& n0) {
  const int wg = (int)blockIdx.x;
  const int swz = (wg & 7) * ((int)gridDim.x >> 3) + (wg >> 3);
  const int mb = swz / nby;
  const int nb = swz - mb * nby;
  m0 = mb * 128;
  n0 = nb * 128;
}

// ---------------------------------------------------------------------------
// GEMM (short-K): 128x128 tile, BK=64, single 32 KB buffer, __syncthreads
// loop, 4 blocks/CU -- occupancy hides epilogue + drain (best for nt<=6).
// XOR-8 chunk source-swizzle -> conflict-free ds_read_b128.
// ---------------------------------------------------------------------------
template <int EPI>
__global__ __launch_bounds__(256, 4) void gemm_kernel(
    const short* __restrict__ A, const short* __restrict__ Bt,
    void* __restrict__ Out, const float* __restrict__ bias,
    const void* __restrict__ resid, int M, int N, int K, int nby) {
  __shared__ __align__(16) short lds[128 * 64 * 2];
  const int t = threadIdx.x;
  const int wave = t >> 6, lane = t & 63;
  const int lrow = lane & 15, quad = lane >> 4;
  const int wm = wave & 1, wn = wave >> 1;
  int m0, n0;
  grid_decode(nby, m0, n0);

  f32x4 acc[4][4] = {};
  const int srow = t >> 3;  // 0..31
  const int spos = t & 7;   // 16B chunk slot within 64-elem row
  const int nt = K >> 6;
  short* ldsA = lds;
  short* ldsB = lds + 128 * 64;

  for (int kt = 0; kt < nt; ++kt) {
    int k0 = kt * 64;
    __syncthreads();
#pragma unroll
    for (int i = 0; i < 4; ++i) {
      int row = i * 32 + srow;
      int ca = spos ^ (row & 7);  // store global chunk ca at slot spos
      async_copy16(A + (size_t)(m0 + row) * K + k0 + ca * 8,
                   ldsA + (i * 32 + wave * 8) * 64);
      async_copy16(Bt + (size_t)(n0 + row) * K + k0 + ca * 8,
                   ldsB + (i * 32 + wave * 8) * 64);
    }
    __syncthreads();
#pragma unroll
    for (int ks = 0; ks < 2; ++ks) {
      const int cb = ks * 4;
      bf16x8 af[4], bfr[4];
#pragma unroll
      for (int i = 0; i < 4; ++i) {
        int ra = wm * 64 + i * 16 + lrow;
        af[i] = *(const bf16x8*)(ldsA + ra * 64 + (((cb + quad) ^ (ra & 7)) * 8));
        int rb = wn * 64 + i * 16 + lrow;
        bfr[i] = *(const bf16x8*)(ldsB + rb * 64 + (((cb + quad) ^ (rb & 7)) * 8));
      }
#pragma unroll
      for (int i = 0; i < 4; ++i)
#pragma unroll
        for (int j = 0; j < 4; ++j)
          acc[i][j] = __builtin_amdgcn_mfma_f32_16x16x32_bf16(af[i], bfr[j],
                                                              acc[i][j], 0, 0, 0);
    }
  }
  gemm_epilogue<EPI>(acc, Out, bias, resid, N, m0, n0, wm, wn, lrow, quad);
}

// ---------------------------------------------------------------------------
// GEMM (long-K, fc2): 128x128 tile, BK=32, THREE 16 KB buffers, depth-3
// pipeline: stage t+2 while computing t; counted vmcnt ladder 8/4/0 keeps
// 2 tiles of loads in flight across barriers.  48 KB LDS -> 3 blocks/CU
// (vs 2 for the BK=64 depth-2 version): more TLP *and* ~2 compute phases of
// LLC/HBM latency cover.  XOR-4 source-swizzle spreads ds_read_b128 over all
// 8 bank-quads (conflict-free).
// ---------------------------------------------------------------------------
template <int EPI>
__global__ __launch_bounds__(256, 3) void gemm_pipe_kernel(
    const short* __restrict__ A, const short* __restrict__ Bt,
    void* __restrict__ Out, const float* __restrict__ bias,
    const void* __restrict__ resid, int M, int N, int K, int nby) {
  __shared__ __align__(16) short lds[3][128 * 32 * 2];  // A then B per buffer
  const int t = threadIdx.x;
  const int wave = t >> 6, lane = t & 63;
  const int lrow = lane & 15, quad = lane >> 4;
  const int wm = wave & 1, wn = wave >> 1;
  int m0, n0;
  grid_decode(nby, m0, n0);

  f32x4 acc[4][4] = {};
  const int srow = t >> 2;  // 0..63
  const int spos = t & 3;   // 16B chunk slot within 32-elem row
  const int nt = K >> 5;

  // 4 async copies / wave / stage (vmcnt unit = 4 per tile)
  auto stage = [&](int buf, int k0) {
    short* la = &lds[buf][0];
    short* lb = la + 128 * 32;
#pragma unroll
    for (int i = 0; i < 2; ++i) {
      int row = i * 64 + srow;
      int ca = spos ^ (row & 3);  // store global chunk ca at slot spos
      async_copy16(A + (size_t)(m0 + row) * K + k0 + ca * 8,
                   la + (i * 64 + wave * 16) * 32);
      async_copy16(Bt + (size_t)(n0 + row) * K + k0 + ca * 8,
                   lb + (i * 64 + wave * 16) * 32);
    }
  };

  auto compute = [&](int buf) {
    short* ldsA = &lds[buf][0];
    short* ldsB = ldsA + 128 * 32;
    bf16x8 af[4], bfr[4];
#pragma unroll
    for (int i = 0; i < 4; ++i) {
      int ra = wm * 64 + i * 16 + lrow;
      af[i] = *(const bf16x8*)(ldsA + ra * 32 + ((quad ^ (ra & 3)) * 8));
      int rb = wn * 64 + i * 16 + lrow;
      bfr[i] = *(const bf16x8*)(ldsB + rb * 32 + ((quad ^ (rb & 3)) * 8));
    }
    __builtin_amdgcn_s_setprio(1);
#pragma unroll
    for (int i = 0; i < 4; ++i)
#pragma unroll
      for (int j = 0; j < 4; ++j)
        acc[i][j] = __builtin_amdgcn_mfma_f32_16x16x32_bf16(af[i], bfr[j],
                                                            acc[i][j], 0, 0, 0);
    __builtin_amdgcn_s_setprio(0);
  };

  stage(0, 0);
  stage(1, 32);
  int cbuf = 0, sbuf = 2;
  for (int kt = 0; kt < nt; ++kt) {
    __builtin_amdgcn_sched_barrier(0);
    if (kt + 2 < nt) {
      stage(sbuf, (kt + 2) * 32);                      // 12 in flight
      asm volatile("s_waitcnt vmcnt(8)" ::: "memory"); // tile kt landed
    } else if (kt + 1 < nt) {
      asm volatile("s_waitcnt vmcnt(4)" ::: "memory");
    } else {
      asm volatile("s_waitcnt vmcnt(0)" ::: "memory");
    }
    __builtin_amdgcn_s_barrier();   // all waves' tile-kt data in LDS
    __builtin_amdgcn_sched_barrier(0);
    compute(cbuf);
    __builtin_amdgcn_sched_barrier(0);
    __builtin_amdgcn_s_barrier();   // all waves done reading buf cbuf
    cbuf = (cbuf == 2) ? 0 : cbuf + 1;
    sbuf = (sbuf == 2) ? 0 : sbuf + 1;
  }
  gemm_epilogue<EPI>(acc, Out, bias, resid, N, m0, n0, wm, wn, lrow, quad);
}

// ---------------------------------------------------------------------------
// Attention: one wave per (window, head).  qkv layout: row (bw*49+t), 1152
// cols = [Q 384 | K 384 | V 384], head h at col h*32.
// ---------------------------------------------------------------------------
__global__ __launch_bounds__(256) void attn_kernel(
    const short* __restrict__ qkv, short* __restrict__ o) {
  __shared__ __align__(16) short plds[4][64 * 72];  // +8 pad per row: no conflicts
  const int wavei = threadIdx.x >> 6;
  const int lane = threadIdx.x & 63;
  const int gw = blockIdx.x * 4 + wavei;       // 0..12287
  const int bw = gw / 12;
  const int h = gw - bw * 12;
  const int w = bw & 63;
  const int lrow = lane & 15, quad = lane >> 4;
  const short* base = qkv + (size_t)bw * 49 * 1152 + h * 32;

  // ---- S = Q K^T ----
  bf16x8 qf[4], kf[4];
#pragma unroll
  for (int i = 0; i < 4; ++i) {
    int tq = i * 16 + lrow;  // rows >=49 read slack (in-bounds), masked later
    const short* p = base + (size_t)tq * 1152 + quad * 8;
    qf[i] = *(const bf16x8*)p;
    kf[i] = *(const bf16x8*)(p + 384);
  }
  f32x4 sa[4][4] = {};
#pragma unroll
  for (int i = 0; i < 4; ++i)
#pragma unroll
    for (int j = 0; j < 4; ++j)
      sa[i][j] = __builtin_amdgcn_mfma_f32_16x16x32_bf16(qf[i], kf[j], sa[i][j], 0, 0, 0);

  // ---- region id for shift-window mask (this lane's token = lane) ----
  int tl = lane < 49 ? lane : 0;
  int rr = tl / 7, cc = tl - rr * 7;
  int hs = (w >> 3) * 7 + rr;
  int ws = (w & 7) * 7 + cc;
  int id = (hs < 49 ? 0 : (hs < 53 ? 3 : 6)) + (ws < 49 ? 0 : (ws < 53 ? 1 : 2));

  int idn[4], idm[4][4];
#pragma unroll
  for (int j = 0; j < 4; ++j) idn[j] = __shfl(id, j * 16 + lrow);
#pragma unroll
  for (int i = 0; i < 4; ++i)
#pragma unroll
    for (int r = 0; r < 4; ++r) idm[i][r] = __shfl(id, i * 16 + quad * 4 + r);

#pragma unroll
  for (int i = 0; i < 4; ++i)
#pragma unroll
    for (int j = 0; j < 4; ++j)
#pragma unroll
      for (int r = 0; r < 4; ++r) {
        float v = sa[i][j][r] * QK_SCALE + (idm[i][r] == idn[j] ? 0.f : -100.f);
        sa[i][j][r] = (j * 16 + lrow < 49) ? v : -1e30f;
      }

  // ---- softmax over rows (16-lane groups) ----
#pragma unroll
  for (int i = 0; i < 4; ++i)
#pragma unroll
    for (int r = 0; r < 4; ++r) {
      float mx = -1e30f;
#pragma unroll
      for (int j = 0; j < 4; ++j) mx = fmaxf(mx, sa[i][j][r]);
#pragma unroll
      for (int m = 1; m < 16; m <<= 1) mx = fmaxf(mx, __shfl_xor(mx, m));
      float sum = 0.f;
#pragma unroll
      for (int j = 0; j < 4; ++j) {
        float e = exp2f((sa[i][j][r] - mx) * 1.44269504f);
        sa[i][j][r] = e;
        sum += e;
      }
#pragma unroll
      for (int m = 1; m < 16; m <<= 1) sum += __shfl_xor(sum, m);
      float inv = 1.0f / sum;
#pragma unroll
      for (int j = 0; j < 4; ++j) sa[i][j][r] *= inv;
    }

  // ---- P -> LDS (C-layout -> row-major bf16, A-operand readable) ----
  short* pw = plds[wavei];
#pragma unroll
  for (int i = 0; i < 4; ++i)
#pragma unroll
    for (int r = 0; r < 4; ++r)
#pragma unroll
      for (int j = 0; j < 4; ++j)
        pw[(i * 16 + quad * 4 + r) * 72 + j * 16 + lrow] = f2bf(sa[i][j][r]);

  // ---- O = P V ----
  f32x4 oa[4][2] = {};
#pragma unroll
  for (int kk = 0; kk < 2; ++kk) {
    bf16x8 vf[2];
#pragma unroll
    for (int j2 = 0; j2 < 2; ++j2) {
#pragma unroll
      for (int jj = 0; jj < 8; ++jj) {
        int n = kk * 32 + quad * 8 + jj;
        vf[j2][jj] = (n < 49)
            ? base[768 + (size_t)n * 1152 + j2 * 16 + lrow]
            : (short)0;
      }
    }
#pragma unroll
    for (int i = 0; i < 4; ++i) {
      bf16x8 pf = *(const bf16x8*)(pw + (i * 16 + lrow) * 72 + kk * 32 + quad * 8);
#pragma unroll
      for (int j2 = 0; j2 < 2; ++j2)
        oa[i][j2] = __builtin_amdgcn_mfma_f32_16x16x32_bf16(pf, vf[j2], oa[i][j2], 0, 0, 0);
    }
  }

#pragma unroll
  for (int i = 0; i < 4; ++i)
#pragma unroll
    for (int j2 = 0; j2 < 2; ++j2)
#pragma unroll
      for (int r = 0; r < 4; ++r) {
        int m = i * 16 + quad * 4 + r;
        if (m < 49)
          o[((size_t)bw * 49 + m) * 384 + h * 32 + j2 * 16 + lrow] = f2bf(oa[i][j2][r]);
      }
}

// ---------------------------------------------------------------------------
extern "C" void kernel_launch(void* const* d_in, const int* in_sizes, int n_in,
                              void* d_out, int out_size, void* d_ws, size_t ws_size,
                              hipStream_t stream) {
  const float* x      = (const float*)d_in[0];
  const float* ln1_g  = (const float*)d_in[1];
  const float* ln1_b  = (const float*)d_in[2];
  const float* qkv_w  = (const float*)d_in[3];
  const float* proj_w = (const float*)d_in[4];
  const float* proj_b = (const float*)d_in[5];
  const float* ln2_g  = (const float*)d_in[6];
  const float* ln2_b  = (const float*)d_in[7];
  const float* fc1_w  = (const float*)d_in[8];
  const float* fc1_b  = (const float*)d_in[9];
  const float* fc2_w  = (const float*)d_in[10];
  const float* fc2_b  = (const float*)d_in[11];
  float* out = (float*)d_out;

  char* ws = (char*)d_ws;
  auto alloc = [&](size_t bytes) {
    char* p = ws;
    ws += (bytes + 255) & ~(size_t)255;
    return p;
  };
  short* qkv_wT  = (short*)alloc((size_t)1152 * 384 * 2);
  short* proj_wT = (short*)alloc((size_t)384 * 384 * 2);
  short* fc1_wT  = (short*)alloc((size_t)1536 * 384 * 2);
  short* fc2_wT  = (short*)alloc((size_t)384 * 1536 * 2);
  short* bufA    = (short*)alloc((size_t)MROWS * 384 * 2);   // y_win / o / m
  short* x1      = (short*)alloc((size_t)MROWS * 384 * 2);   // bf16 residual
  short* bufB    = (short*)alloc((size_t)MROWS * 1536 * 2);  // qkv / fc1 act

  // weights -> bf16 transposed
  transpose_cast<<<(384 * 1152) / 256, 256, 0, stream>>>(qkv_w, qkv_wT, 384, 1152);
  transpose_cast<<<(384 * 384) / 256, 256, 0, stream>>>(proj_w, proj_wT, 384, 384);
  transpose_cast<<<(384 * 1536) / 256, 256, 0, stream>>>(fc1_w, fc1_wT, 384, 1536);
  transpose_cast<<<(1536 * 384) / 256, 256, 0, stream>>>(fc2_w, fc2_wT, 1536, 384);

  // LN1 + shift + window partition
  ln_kernel<float><<<MROWS / 4, 256, 0, stream>>>(x, ln1_g, ln1_b, bufA, 1);

  // qkv = y @ qkv_w  (50176 x 1152), K=384
  gemm_kernel<0><<<392 * 9, 256, 0, stream>>>(bufA, qkv_wT, bufB, nullptr,
                                              nullptr, MROWS, 1152, 384, 9);

  // attention -> o (windowed layout) into bufA
  attn_kernel<<<3072, 256, 0, stream>>>(bufB, bufA);

  // x1 = x + (o @ proj_w + proj_b) window-reversed  (bf16 out), K=384
  gemm_kernel<1><<<392 * 3, 256, 0, stream>>>(bufA, proj_wT, x1, proj_b,
                                              x, MROWS, 384, 384, 3);

  // m = LN2(x1)
  ln_kernel<short><<<MROWS / 4, 256, 0, stream>>>(x1, ln2_g, ln2_b, bufA, 0);

  // a1 = gelu(m @ fc1_w + fc1_b)  (50176 x 1536), K=384
  gemm_kernel<2><<<392 * 12, 256, 0, stream>>>(bufA, fc1_wT, bufB, fc1_b,
                                               nullptr, MROWS, 1536, 384, 12);

  // out = x1 + gelu(a1 @ fc2_w + fc2_b), K=1536 -> depth-3 BK=32 pipeline
  gemm_pipe_kernel<3><<<392 * 3, 256, 0, stream>>>(bufB, fc2_wT, out, fc2_b,
                                                   x1, MROWS, 384, 1536, 3);
}